// Round 21
// baseline (609.509 us; speedup 1.0000x reference)
//
#include <hip/hip_runtime.h>
#include <math.h>

#define N_LOCS 16384
#define START 4096
#define NB 12288
#define NMAT 96
#define KDIM 60

typedef __attribute__((ext_vector_type(8))) short short8;
typedef __attribute__((ext_vector_type(4))) float f32x4;

#define SBAR __builtin_amdgcn_sched_barrier(0)

__global__ void minnz_kernel(const float* __restrict__ scales, unsigned* __restrict__ ws) {
    int idx = blockIdx.x * 256 + threadIdx.x;
    if (idx < NB) {
        float v = scales[START + idx];
        if (v != 0.0f) atomicMin(ws, __float_as_uint(v));
    }
}

__device__ __forceinline__ unsigned short f32_to_bf16_rne(float f, float* back) {
    unsigned u = __float_as_uint(f);
    unsigned r = (u + 0x7fffu + ((u >> 16) & 1u)) >> 16;
    *back = __uint_as_float(r << 16);
    return (unsigned short)r;
}

// ============ kernel 1: gram + transform + write g (r18-verified, unchanged) ============
__launch_bounds__(256)
__global__ void gram_kernel(const float* __restrict__ kp,
                            const float* __restrict__ aug,
                            const float* __restrict__ scales,
                            const float* __restrict__ nug,
                            const unsigned* __restrict__ ws,
                            float* __restrict__ out)
{
    const int b = blockIdx.x;
    const int t = threadIdx.x;
    const int ti = t >> 4, tj = t & 15;

    float* outG = out;                                   // [NB][96][96]
    float* outN = out + 2 * (size_t)NB * NMAT * NMAT;    // [NB]

    if (t == 0) outN[b] = nug[b];

    const size_t gbase = (size_t)b * (NMAT * NMAT);

    if (b == 0) {
        #pragma unroll
        for (int u = 0; u < 6; ++u) {
            int i = ti * 6 + u;
            #pragma unroll
            for (int v = 0; v < 6; ++v) {
                int j = tj * 6 + v;
                outG[gbase + (size_t)i * NMAT + j] = (i == j) ? 1.0f : 0.0f;
            }
        }
        return;
    }

    __shared__ char smem[37632];
    unsigned short* sxh  = (unsigned short*)smem;
    unsigned short* sxl  = (unsigned short*)(smem + 13824);
    float*          slin = (float*)smem;

    const float kp1 = kp[1], kp3 = kp[3], kp5 = kp[5], kp7 = kp[7];
    const float kp8 = kp[8], kp9 = kp[9], kp11 = kp[11];
    float sc = scales[START + b];
    if (sc == 0.0f) sc = __uint_as_float(ws[0]) * 0.5f;
    const float sigma   = __expf(kp1 + kp3 * __logf(sc));
    const float sigma2  = sigma * sigma;
    const float inv_ls2 = 1.0f / (3.0f * __expf(2.0f * kp11));
    const float inv_nug = 1.0f / nug[b];

    const int c = t & 63;
    float myscale = 0.0f;
    if (c < KDIM) {
        float kf = (c < 30) ? (float)(c + 1) : (float)(c - 29);
        float th = (c < 30) ? kp5 : kp8;
        float de = (c < 30) ? kp7 : kp9;
        myscale = __expf(th - 0.5f * __expf(de) * kf);
    }

    {
        const int rgrp = t >> 6;
        const size_t rowstride = (size_t)N_LOCS * 61;
        const size_t base = (size_t)(START + b) * 61 + 1 + c;
        #pragma unroll
        for (int half = 0; half < 2; ++half) {
            float vb[12];
            #pragma unroll
            for (int it = 0; it < 12; ++it) {
                int i = (half * 12 + it) * 4 + rgrp;
                vb[it] = (c < KDIM) ? aug[base + (size_t)i * rowstride] : 0.0f;
            }
            #pragma unroll
            for (int it = 0; it < 12; ++it) {
                int i = (half * 12 + it) * 4 + rgrp;
                float v = vb[it];
                v = (v != v) ? 0.0f : v;
                v *= myscale;
                float fh;
                unsigned short hb = f32_to_bf16_rne(v, &fh);
                float dummy;
                unsigned short lb = f32_to_bf16_rne(v - fh, &dummy);
                sxh[i * 72 + c] = hb;
                sxl[i * 72 + c] = lb;
            }
        }
    }
    __syncthreads();

    {
        const int w  = t >> 6;
        const int l  = t & 63;
        const int wrB = (w >> 1) * 48;
        const int wcB = (w & 1) * 48;
        const int lrow = l & 15;
        const int lk   = (l >> 4) * 8;

        f32x4 gacc[3][3];
        #pragma unroll
        for (int a = 0; a < 3; ++a)
            #pragma unroll
            for (int cc = 0; cc < 3; ++cc) gacc[a][cc] = (f32x4){0.f, 0.f, 0.f, 0.f};

        #pragma unroll
        for (int k0 = 0; k0 < 64; k0 += 32) {
            #pragma unroll
            for (int a = 0; a < 3; ++a) {
                int arow = wrB + a * 16 + lrow;
                short8 Ah = *(const short8*)&sxh[arow * 72 + k0 + lk];
                short8 Al = *(const short8*)&sxl[arow * 72 + k0 + lk];
                #pragma unroll
                for (int cc = 0; cc < 3; ++cc) {
                    int brow = wcB + cc * 16 + lrow;
                    short8 Bh = *(const short8*)&sxh[brow * 72 + k0 + lk];
                    short8 Bl = *(const short8*)&sxl[brow * 72 + k0 + lk];
                    gacc[a][cc] = __builtin_amdgcn_mfma_f32_16x16x32_bf16(Ah, Bh, gacc[a][cc], 0, 0, 0);
                    gacc[a][cc] = __builtin_amdgcn_mfma_f32_16x16x32_bf16(Ah, Bl, gacc[a][cc], 0, 0, 0);
                    gacc[a][cc] = __builtin_amdgcn_mfma_f32_16x16x32_bf16(Al, Bh, gacc[a][cc], 0, 0, 0);
                    gacc[a][cc] = __builtin_amdgcn_mfma_f32_16x16x32_bf16(Al, Bl, gacc[a][cc], 0, 0, 0);
                }
            }
        }
        __syncthreads();

        #pragma unroll
        for (int a = 0; a < 3; ++a)
            #pragma unroll
            for (int cc = 0; cc < 3; ++cc) {
                int col = wcB + cc * 16 + lrow;
                #pragma unroll
                for (int r = 0; r < 4; ++r) {
                    int row = wrB + a * 16 + (l >> 4) * 4 + r;
                    slin[row * 98 + col] = gacc[a][cc][r];
                }
            }
    }
    __syncthreads();

    float acc[6][6];
    #pragma unroll
    for (int u = 0; u < 6; ++u) {
        int rb = (ti * 6 + u) * 98;
        #pragma unroll
        for (int v = 0; v < 6; v += 2) {
            float2 p = *(const float2*)&slin[rb + tj * 6 + v];
            acc[u][v] = p.x; acc[u][v + 1] = p.y;
        }
    }
    float di[6], dj[6];
    #pragma unroll
    for (int u = 0; u < 6; ++u) { int i = ti * 6 + u; di[u] = slin[i * 98 + i]; }
    #pragma unroll
    for (int v = 0; v < 6; ++v) { int j = tj * 6 + v; dj[v] = slin[j * 98 + j]; }

    #pragma unroll
    for (int u = 0; u < 6; ++u) {
        int i = ti * 6 + u;
        #pragma unroll
        for (int v = 0; v < 6; ++v) {
            int j = tj * 6 + v;
            float lin = acc[u][v];
            float d2 = (di[u] + dj[v] - 2.0f * lin) * inv_ls2;
            d2 = fmaxf(d2, 0.0f);
            float cc = sqrtf(3.0f * d2);
            float nl = (1.0f + cc) * __expf(-cc);
            acc[u][v] = fmaf(sigma2, nl, lin) * inv_nug + ((i == j) ? 1.0f : 0.0f);
        }
    }
    #pragma unroll
    for (int u = 0; u < 6; ++u) {
        size_t row = gbase + (size_t)(ti * 6 + u) * NMAT + tj * 6;
        #pragma unroll
        for (int v = 0; v < 6; v += 2) {
            *(float2*)&outG[row + v] = make_float2(acc[u][v], acc[u][v + 1]);
        }
    }
}

// ====== kernel 2: WAVE-PER-MATRIX cholesky — r20-verified skeleton ======
// ONLY delta vs r20 (PASSED, 608us): the deferred-C11 loop (pure LDS READS,
// Pbuf fully written before the preceding SBAR, zero LDS writes inside) drops
// its per-iteration SBARs and unrolls 2x, letting the scheduler overlap
// iteration k+1's ds_reads with iteration k's fmas. All write->read-bearing
// SBARs retained. Same jb-asc/m-asc fma order -> bitwise-identical values.

#define PHASE_A(D) do {                                                          \
    _Pragma("unroll") for (int c2 = 0; c2 < 6; ++c2) {                           \
        float s = D[c2][c2];                                                     \
        _Pragma("unroll") for (int m = 0; m < 6; ++m) if (m < c2) s -= D[c2][m] * D[c2][m]; \
        float l = sqrtf(s);                                                      \
        D[c2][c2] = l;                                                           \
        float rinv = 1.0f / l;                                                   \
        rinvp[c2] = rinv;                                                        \
        _Pragma("unroll") for (int rr = 0; rr < 6; ++rr) if (rr > c2) {          \
            float s2 = D[rr][c2];                                                \
            _Pragma("unroll") for (int m = 0; m < 6; ++m) if (m < c2) s2 -= D[rr][m] * D[c2][m]; \
            D[rr][c2] = s2 * rinv;                                               \
        }                                                                        \
    }                                                                            \
    _Pragma("unroll") for (int u = 0; u < 6; ++u) {                              \
        *(float4*)&L6p[u * 8]     = make_float4(D[u][0], D[u][1], D[u][2], D[u][3]); \
        *(float2*)&L6p[u * 8 + 4] = make_float2(D[u][4], D[u][5]);               \
    }                                                                            \
} while (0)

#define PHASE_B_SOLVE(D) do {                                                    \
    _Pragma("unroll") for (int c2 = 0; c2 < 6; ++c2) {                           \
        float4 p = *(const float4*)&L6p[c2 * 8];                                 \
        float2 q = *(const float2*)&L6p[c2 * 8 + 4];                             \
        float a0 = p.x, a1 = p.y, a2 = p.z, a3 = p.w, a4 = q.x;                  \
        (void)q;                                                                 \
        float rinv = rinvp[c2];                                                  \
        _Pragma("unroll") for (int u = 0; u < 6; ++u) {                          \
            float s = D[u][c2];                                                  \
            if (c2 > 0) s -= D[u][0] * a0;                                       \
            if (c2 > 1) s -= D[u][1] * a1;                                       \
            if (c2 > 2) s -= D[u][2] * a2;                                       \
            if (c2 > 3) s -= D[u][3] * a3;                                       \
            if (c2 > 4) s -= D[u][4] * a4;                                       \
            D[u][c2] = s * rinv;                                                 \
        }                                                                        \
    }                                                                            \
} while (0)

#define PHASE_B(D, PROW) do {                                                    \
    PHASE_B_SOLVE(D);                                                            \
    _Pragma("unroll") for (int u = 0; u < 6; ++u) {                              \
        int prow = (PROW) * 6 + u;                                               \
        *(float4*)&panel[prow * 12]     = make_float4(D[u][0], D[u][1], D[u][2], D[u][3]); \
        *(float2*)&panel[prow * 12 + 4] = make_float2(D[u][4], D[u][5]);         \
    }                                                                            \
} while (0)

#define PERSIST10(D, CB) do {                                                    \
    _Pragma("unroll") for (int u = 0; u < 6; ++u)                                \
        _Pragma("unroll") for (int x = 0; x < 6; ++x)                            \
            Pbuf[(wi * 6 + u) * 49 + (CB) + x] = D[u][x];                        \
} while (0)

#define PHASE_C(D, TIEFF, TJEFF) do {                                            \
    _Pragma("unroll") for (int m = 0; m < 6; ++m) {                              \
        float pum[6], pvm[6];                                                    \
        _Pragma("unroll") for (int u = 0; u < 6; ++u)                            \
            pum[u] = panel[((TIEFF) * 6 + u) * 12 + m];                          \
        _Pragma("unroll") for (int v = 0; v < 6; ++v)                            \
            pvm[v] = panel[((TJEFF) * 6 + v) * 12 + m];                          \
        _Pragma("unroll") for (int u = 0; u < 6; ++u)                            \
            _Pragma("unroll") for (int v = 0; v < 6; ++v)                        \
                D[u][v] = fmaf(-pum[u], pvm[v], D[u][v]);                        \
    }                                                                            \
} while (0)

#define PHASE_C_MIX(D, RU, RV, CB) do {                                          \
    _Pragma("unroll") for (int m = 0; m < 6; ++m) {                              \
        float pum[6], pvm[6];                                                    \
        _Pragma("unroll") for (int u = 0; u < 6; ++u)                            \
            pum[u] = Pbuf[((RU) * 6 + u) * 49 + (CB) + m];                       \
        _Pragma("unroll") for (int v = 0; v < 6; ++v)                            \
            pvm[v] = panel[((RV) * 6 + v) * 12 + m];                             \
        _Pragma("unroll") for (int u = 0; u < 6; ++u)                            \
            _Pragma("unroll") for (int v = 0; v < 6; ++v)                        \
                D[u][v] = fmaf(-pum[u], pvm[v], D[u][v]);                        \
    }                                                                            \
} while (0)

#define PHASE_C_P(D, RU, RV, CB) do {                                            \
    _Pragma("unroll") for (int m = 0; m < 6; ++m) {                              \
        float pum[6], pvm[6];                                                    \
        _Pragma("unroll") for (int u = 0; u < 6; ++u)                            \
            pum[u] = Pbuf[((RU) * 6 + u) * 49 + (CB) + m];                       \
        _Pragma("unroll") for (int v = 0; v < 6; ++v)                            \
            pvm[v] = Pbuf[((RV) * 6 + v) * 49 + (CB) + m];                       \
        _Pragma("unroll") for (int u = 0; u < 6; ++u)                            \
            _Pragma("unroll") for (int v = 0; v < 6; ++v)                        \
                D[u][v] = fmaf(-pum[u], pvm[v], D[u][v]);                        \
    }                                                                            \
} while (0)

#define STORE_TILE(D, TIEFF, TJEFF) do {                                         \
    _Pragma("unroll") for (int u = 0; u < 6; ++u) {                              \
        const int i2 = (TIEFF) * 6 + u;                                          \
        size_t rowp = gbase + (size_t)i2 * NMAT + (TJEFF) * 6;                   \
        _Pragma("unroll") for (int v = 0; v < 6; v += 2) {                       \
            int j0 = (TJEFF) * 6 + v;                                            \
            float a0 = D[u][v], a1 = D[u][v + 1];                                \
            if ((TIEFF) < (TJEFF)) { a0 = 0.0f; a1 = 0.0f; }                     \
            else if ((TIEFF) == (TJEFF)) {                                       \
                if (j0 > i2)     a0 = 0.0f;                                      \
                if (j0 + 1 > i2) a1 = 0.0f;                                      \
            }                                                                    \
            *(float2*)&outL[rowp + v] = make_float2(a0, a1);                     \
        }                                                                        \
    }                                                                            \
} while (0)

#define LOAD_TILE(D, TIEFF, TJEFF) do {                                          \
    _Pragma("unroll") for (int u = 0; u < 6; ++u) {                              \
        size_t rowp = gbase + (size_t)((TIEFF) * 6 + u) * NMAT + (TJEFF) * 6;    \
        float2 p0 = *(const float2*)&outG[rowp + 0];                             \
        float2 p1 = *(const float2*)&outG[rowp + 2];                             \
        float2 p2 = *(const float2*)&outG[rowp + 4];                             \
        D[u][0] = p0.x; D[u][1] = p0.y; D[u][2] = p1.x;                          \
        D[u][3] = p1.y; D[u][4] = p2.x; D[u][5] = p2.y;                          \
    }                                                                            \
} while (0)

__launch_bounds__(256)
__global__ void chol_kernel(const float* __restrict__ outG,
                            float* __restrict__ outL)
{
    const int w    = threadIdx.x >> 6;   // wave id 0..3 -> matrix
    const int lane = threadIdx.x & 63;
    const int wi   = lane >> 3;          // 0..7 row-tile
    const int wj   = lane & 7;           // 0..7 col-tile
    const int b    = blockIdx.x * 4 + w;
    const size_t gbase = (size_t)b * (NMAT * NMAT);

    __shared__ float spanel_all[4][48][12];  // transient panel (rows 0..47)
    __shared__ float sPbuf_all[4][48][49];   // persistent T10/T11 panels
    __shared__ float sL6_all[4][6][8];
    __shared__ float srinv_all[4][8];
    float* panel = &spanel_all[w][0][0];
    float* Pbuf  = &sPbuf_all[w][0][0];
    float* L6p   = &sL6_all[w][0][0];
    float* rinvp = &srinv_all[w][0];

    float acc00[6][6], acc10[6][6];

    LOAD_TILE(acc00, wi,     wj);
    LOAD_TILE(acc10, 8 + wi, wj);

    // ---- first half: factor T00, solve T10 panels (persist-only to Pbuf) ----
    #pragma unroll 1
    for (int jb = 0; jb < 8; ++jb) {
        const int J = jb;
        if (wi == J && wj == J) PHASE_A(acc00);
        SBAR;
        if (wj == J && wi > J) PHASE_B(acc00, wi);
        if (wj == J)           { PHASE_B_SOLVE(acc10); PERSIST10(acc10, J * 6); }
        SBAR;
        if (wj > J && wi >= wj) PHASE_C(acc00, wi, wj);
        if (wj > J)             PHASE_C_MIX(acc10, wi, wj, J * 6);
        SBAR;
    }

    // ---- acc00/acc10 final: store, freeing registers ----
    STORE_TILE(acc00, wi,     wj);
    STORE_TILE(acc10, 8 + wi, wj);
    #pragma unroll
    for (int u = 0; u < 6; ++u) {
        size_t rowp = gbase + (size_t)(wi * 6 + u) * NMAT + (8 + wj) * 6;
        *(float2*)&outL[rowp + 0] = make_float2(0.0f, 0.0f);
        *(float2*)&outL[rowp + 2] = make_float2(0.0f, 0.0f);
        *(float2*)&outL[rowp + 4] = make_float2(0.0f, 0.0f);
    }
    SBAR;

    // ---- load g11; apply the 8 deferred rank-6 updates (jb asc, m asc) ----
    // READ-ONLY region: Pbuf fully written before the SBAR above; no LDS
    // writes inside -> per-iteration SBARs removed, unroll 2 for load ILP.
    float acc11[6][6];
    LOAD_TILE(acc11, 8 + wi, 8 + wj);
    #pragma unroll 2
    for (int jb2 = 0; jb2 < 8; ++jb2) {
        if (wi >= wj) PHASE_C_P(acc11, wi, wj, jb2 * 6);
    }
    SBAR;

    // ---- second half: panel rows shifted -48 (address-only change) ----
    #pragma unroll 1
    for (int jb = 8; jb < 16; ++jb) {
        const int J = jb - 8;
        if (wi == J && wj == J) PHASE_A(acc11);
        SBAR;
        if (wj == J && wi > J) PHASE_B(acc11, wi);
        SBAR;
        if (wj > J && wi >= wj) PHASE_C(acc11, wi, wj);
        SBAR;
    }

    STORE_TILE(acc11, 8 + wi, 8 + wj);
}

extern "C" void kernel_launch(void* const* d_in, const int* in_sizes, int n_in,
                              void* d_out, int out_size, void* d_ws, size_t ws_size,
                              hipStream_t stream) {
    const float* kp     = (const float*)d_in[0];
    const float* aug    = (const float*)d_in[1];
    const float* scales = (const float*)d_in[2];
    const float* nug    = (const float*)d_in[3];
    float* out = (float*)d_out;
    unsigned* ws = (unsigned*)d_ws;

    float* outG = out;
    float* outL = out + (size_t)NB * NMAT * NMAT;

    hipMemsetAsync(ws, 0xFF, 4, stream);
    minnz_kernel<<<(NB + 255) / 256, 256, 0, stream>>>(scales, ws);
    gram_kernel<<<NB, 256, 0, stream>>>(kp, aug, scales, nug, ws, out);
    chol_kernel<<<NB / 4, 256, 0, stream>>>(outG, outL);
}

// Round 22
// 606.515 us; speedup vs baseline: 1.0049x; 1.0049x over previous
//
#include <hip/hip_runtime.h>
#include <math.h>

#define N_LOCS 16384
#define START 4096
#define NB 12288
#define NMAT 96
#define KDIM 60

typedef __attribute__((ext_vector_type(8))) short short8;
typedef __attribute__((ext_vector_type(4))) float f32x4;

#define SBAR __builtin_amdgcn_sched_barrier(0)

__global__ void minnz_kernel(const float* __restrict__ scales, unsigned* __restrict__ ws) {
    int idx = blockIdx.x * 256 + threadIdx.x;
    if (idx < NB) {
        float v = scales[START + idx];
        if (v != 0.0f) atomicMin(ws, __float_as_uint(v));
    }
}

__device__ __forceinline__ unsigned short f32_to_bf16_rne(float f, float* back) {
    unsigned u = __float_as_uint(f);
    unsigned r = (u + 0x7fffu + ((u >> 16) & 1u)) >> 16;
    *back = __uint_as_float(r << 16);
    return (unsigned short)r;
}

// ============ kernel 1: gram + transform + write g (r18-verified, unchanged) ============
__launch_bounds__(256)
__global__ void gram_kernel(const float* __restrict__ kp,
                            const float* __restrict__ aug,
                            const float* __restrict__ scales,
                            const float* __restrict__ nug,
                            const unsigned* __restrict__ ws,
                            float* __restrict__ out)
{
    const int b = blockIdx.x;
    const int t = threadIdx.x;
    const int ti = t >> 4, tj = t & 15;

    float* outG = out;                                   // [NB][96][96]
    float* outN = out + 2 * (size_t)NB * NMAT * NMAT;    // [NB]

    if (t == 0) outN[b] = nug[b];

    const size_t gbase = (size_t)b * (NMAT * NMAT);

    if (b == 0) {
        #pragma unroll
        for (int u = 0; u < 6; ++u) {
            int i = ti * 6 + u;
            #pragma unroll
            for (int v = 0; v < 6; ++v) {
                int j = tj * 6 + v;
                outG[gbase + (size_t)i * NMAT + j] = (i == j) ? 1.0f : 0.0f;
            }
        }
        return;
    }

    __shared__ char smem[37632];
    unsigned short* sxh  = (unsigned short*)smem;
    unsigned short* sxl  = (unsigned short*)(smem + 13824);
    float*          slin = (float*)smem;

    const float kp1 = kp[1], kp3 = kp[3], kp5 = kp[5], kp7 = kp[7];
    const float kp8 = kp[8], kp9 = kp[9], kp11 = kp[11];
    float sc = scales[START + b];
    if (sc == 0.0f) sc = __uint_as_float(ws[0]) * 0.5f;
    const float sigma   = __expf(kp1 + kp3 * __logf(sc));
    const float sigma2  = sigma * sigma;
    const float inv_ls2 = 1.0f / (3.0f * __expf(2.0f * kp11));
    const float inv_nug = 1.0f / nug[b];

    const int c = t & 63;
    float myscale = 0.0f;
    if (c < KDIM) {
        float kf = (c < 30) ? (float)(c + 1) : (float)(c - 29);
        float th = (c < 30) ? kp5 : kp8;
        float de = (c < 30) ? kp7 : kp9;
        myscale = __expf(th - 0.5f * __expf(de) * kf);
    }

    {
        const int rgrp = t >> 6;
        const size_t rowstride = (size_t)N_LOCS * 61;
        const size_t base = (size_t)(START + b) * 61 + 1 + c;
        #pragma unroll
        for (int half = 0; half < 2; ++half) {
            float vb[12];
            #pragma unroll
            for (int it = 0; it < 12; ++it) {
                int i = (half * 12 + it) * 4 + rgrp;
                vb[it] = (c < KDIM) ? aug[base + (size_t)i * rowstride] : 0.0f;
            }
            #pragma unroll
            for (int it = 0; it < 12; ++it) {
                int i = (half * 12 + it) * 4 + rgrp;
                float v = vb[it];
                v = (v != v) ? 0.0f : v;
                v *= myscale;
                float fh;
                unsigned short hb = f32_to_bf16_rne(v, &fh);
                float dummy;
                unsigned short lb = f32_to_bf16_rne(v - fh, &dummy);
                sxh[i * 72 + c] = hb;
                sxl[i * 72 + c] = lb;
            }
        }
    }
    __syncthreads();

    {
        const int w  = t >> 6;
        const int l  = t & 63;
        const int wrB = (w >> 1) * 48;
        const int wcB = (w & 1) * 48;
        const int lrow = l & 15;
        const int lk   = (l >> 4) * 8;

        f32x4 gacc[3][3];
        #pragma unroll
        for (int a = 0; a < 3; ++a)
            #pragma unroll
            for (int cc = 0; cc < 3; ++cc) gacc[a][cc] = (f32x4){0.f, 0.f, 0.f, 0.f};

        #pragma unroll
        for (int k0 = 0; k0 < 64; k0 += 32) {
            #pragma unroll
            for (int a = 0; a < 3; ++a) {
                int arow = wrB + a * 16 + lrow;
                short8 Ah = *(const short8*)&sxh[arow * 72 + k0 + lk];
                short8 Al = *(const short8*)&sxl[arow * 72 + k0 + lk];
                #pragma unroll
                for (int cc = 0; cc < 3; ++cc) {
                    int brow = wcB + cc * 16 + lrow;
                    short8 Bh = *(const short8*)&sxh[brow * 72 + k0 + lk];
                    short8 Bl = *(const short8*)&sxl[brow * 72 + k0 + lk];
                    gacc[a][cc] = __builtin_amdgcn_mfma_f32_16x16x32_bf16(Ah, Bh, gacc[a][cc], 0, 0, 0);
                    gacc[a][cc] = __builtin_amdgcn_mfma_f32_16x16x32_bf16(Ah, Bl, gacc[a][cc], 0, 0, 0);
                    gacc[a][cc] = __builtin_amdgcn_mfma_f32_16x16x32_bf16(Al, Bh, gacc[a][cc], 0, 0, 0);
                    gacc[a][cc] = __builtin_amdgcn_mfma_f32_16x16x32_bf16(Al, Bl, gacc[a][cc], 0, 0, 0);
                }
            }
        }
        __syncthreads();

        #pragma unroll
        for (int a = 0; a < 3; ++a)
            #pragma unroll
            for (int cc = 0; cc < 3; ++cc) {
                int col = wcB + cc * 16 + lrow;
                #pragma unroll
                for (int r = 0; r < 4; ++r) {
                    int row = wrB + a * 16 + (l >> 4) * 4 + r;
                    slin[row * 98 + col] = gacc[a][cc][r];
                }
            }
    }
    __syncthreads();

    float acc[6][6];
    #pragma unroll
    for (int u = 0; u < 6; ++u) {
        int rb = (ti * 6 + u) * 98;
        #pragma unroll
        for (int v = 0; v < 6; v += 2) {
            float2 p = *(const float2*)&slin[rb + tj * 6 + v];
            acc[u][v] = p.x; acc[u][v + 1] = p.y;
        }
    }
    float di[6], dj[6];
    #pragma unroll
    for (int u = 0; u < 6; ++u) { int i = ti * 6 + u; di[u] = slin[i * 98 + i]; }
    #pragma unroll
    for (int v = 0; v < 6; ++v) { int j = tj * 6 + v; dj[v] = slin[j * 98 + j]; }

    #pragma unroll
    for (int u = 0; u < 6; ++u) {
        int i = ti * 6 + u;
        #pragma unroll
        for (int v = 0; v < 6; ++v) {
            int j = tj * 6 + v;
            float lin = acc[u][v];
            float d2 = (di[u] + dj[v] - 2.0f * lin) * inv_ls2;
            d2 = fmaxf(d2, 0.0f);
            float cc = sqrtf(3.0f * d2);
            float nl = (1.0f + cc) * __expf(-cc);
            acc[u][v] = fmaf(sigma2, nl, lin) * inv_nug + ((i == j) ? 1.0f : 0.0f);
        }
    }
    #pragma unroll
    for (int u = 0; u < 6; ++u) {
        size_t row = gbase + (size_t)(ti * 6 + u) * NMAT + tj * 6;
        #pragma unroll
        for (int v = 0; v < 6; v += 2) {
            *(float2*)&outG[row + v] = make_float2(acc[u][v], acc[u][v + 1]);
        }
    }
}

// ====== kernel 2: WAVE-PER-MATRIX cholesky — r21-verified skeleton ======
// Deltas vs r21 (PASSED, 609us):
//   1. Pbuf stride 49 -> 50 (even) — address-only change; scalar writes kept.
//   2. Deferred-C11 loop uses the r13-hardware-verified row-outer PHASE_C form
//      with float2 Pbuf reads (72 scalar -> 36 vector reads per call). Only
//      acc11 is live there, so pu[6][6]+pv[6][6] temps fit. Same per-element
//      jb-asc/m-asc fma order -> bitwise-identical values.
// All SBARs and write->read-bearing phases unchanged.

#define PHASE_A(D) do {                                                          \
    _Pragma("unroll") for (int c2 = 0; c2 < 6; ++c2) {                           \
        float s = D[c2][c2];                                                     \
        _Pragma("unroll") for (int m = 0; m < 6; ++m) if (m < c2) s -= D[c2][m] * D[c2][m]; \
        float l = sqrtf(s);                                                      \
        D[c2][c2] = l;                                                           \
        float rinv = 1.0f / l;                                                   \
        rinvp[c2] = rinv;                                                        \
        _Pragma("unroll") for (int rr = 0; rr < 6; ++rr) if (rr > c2) {          \
            float s2 = D[rr][c2];                                                \
            _Pragma("unroll") for (int m = 0; m < 6; ++m) if (m < c2) s2 -= D[rr][m] * D[c2][m]; \
            D[rr][c2] = s2 * rinv;                                               \
        }                                                                        \
    }                                                                            \
    _Pragma("unroll") for (int u = 0; u < 6; ++u) {                              \
        *(float4*)&L6p[u * 8]     = make_float4(D[u][0], D[u][1], D[u][2], D[u][3]); \
        *(float2*)&L6p[u * 8 + 4] = make_float2(D[u][4], D[u][5]);               \
    }                                                                            \
} while (0)

#define PHASE_B_SOLVE(D) do {                                                    \
    _Pragma("unroll") for (int c2 = 0; c2 < 6; ++c2) {                           \
        float4 p = *(const float4*)&L6p[c2 * 8];                                 \
        float2 q = *(const float2*)&L6p[c2 * 8 + 4];                             \
        float a0 = p.x, a1 = p.y, a2 = p.z, a3 = p.w, a4 = q.x;                  \
        (void)q;                                                                 \
        float rinv = rinvp[c2];                                                  \
        _Pragma("unroll") for (int u = 0; u < 6; ++u) {                          \
            float s = D[u][c2];                                                  \
            if (c2 > 0) s -= D[u][0] * a0;                                       \
            if (c2 > 1) s -= D[u][1] * a1;                                       \
            if (c2 > 2) s -= D[u][2] * a2;                                       \
            if (c2 > 3) s -= D[u][3] * a3;                                       \
            if (c2 > 4) s -= D[u][4] * a4;                                       \
            D[u][c2] = s * rinv;                                                 \
        }                                                                        \
    }                                                                            \
} while (0)

#define PHASE_B(D, PROW) do {                                                    \
    PHASE_B_SOLVE(D);                                                            \
    _Pragma("unroll") for (int u = 0; u < 6; ++u) {                              \
        int prow = (PROW) * 6 + u;                                               \
        *(float4*)&panel[prow * 12]     = make_float4(D[u][0], D[u][1], D[u][2], D[u][3]); \
        *(float2*)&panel[prow * 12 + 4] = make_float2(D[u][4], D[u][5]);         \
    }                                                                            \
} while (0)

#define PERSIST10(D, CB) do {                                                    \
    _Pragma("unroll") for (int u = 0; u < 6; ++u)                                \
        _Pragma("unroll") for (int x = 0; x < 6; ++x)                            \
            Pbuf[(wi * 6 + u) * 50 + (CB) + x] = D[u][x];                        \
} while (0)

#define PHASE_C(D, TIEFF, TJEFF) do {                                            \
    _Pragma("unroll") for (int m = 0; m < 6; ++m) {                              \
        float pum[6], pvm[6];                                                    \
        _Pragma("unroll") for (int u = 0; u < 6; ++u)                            \
            pum[u] = panel[((TIEFF) * 6 + u) * 12 + m];                          \
        _Pragma("unroll") for (int v = 0; v < 6; ++v)                            \
            pvm[v] = panel[((TJEFF) * 6 + v) * 12 + m];                          \
        _Pragma("unroll") for (int u = 0; u < 6; ++u)                            \
            _Pragma("unroll") for (int v = 0; v < 6; ++v)                        \
                D[u][v] = fmaf(-pum[u], pvm[v], D[u][v]);                        \
    }                                                                            \
} while (0)

#define PHASE_C_MIX(D, RU, RV, CB) do {                                          \
    _Pragma("unroll") for (int m = 0; m < 6; ++m) {                              \
        float pum[6], pvm[6];                                                    \
        _Pragma("unroll") for (int u = 0; u < 6; ++u)                            \
            pum[u] = Pbuf[((RU) * 6 + u) * 50 + (CB) + m];                       \
        _Pragma("unroll") for (int v = 0; v < 6; ++v)                            \
            pvm[v] = panel[((RV) * 6 + v) * 12 + m];                             \
        _Pragma("unroll") for (int u = 0; u < 6; ++u)                            \
            _Pragma("unroll") for (int v = 0; v < 6; ++v)                        \
                D[u][v] = fmaf(-pum[u], pvm[v], D[u][v]);                        \
    }                                                                            \
} while (0)

// Deferred C11: row-outer (r13-verified form), float2 Pbuf reads. Each
// D[u][v] receives its 6 fmas in m=0..5 order -> bitwise-identical.
#define PHASE_C_PV(D, RU, RV, CB) do {                                           \
    float pu[6][6], pv[6][6];                                                    \
    _Pragma("unroll") for (int u = 0; u < 6; ++u) {                              \
        int pb = ((RU) * 6 + u) * 50 + (CB);                                     \
        float2 r0 = *(const float2*)&Pbuf[pb + 0];                               \
        float2 r1 = *(const float2*)&Pbuf[pb + 2];                               \
        float2 r2 = *(const float2*)&Pbuf[pb + 4];                               \
        pu[u][0] = r0.x; pu[u][1] = r0.y; pu[u][2] = r1.x;                       \
        pu[u][3] = r1.y; pu[u][4] = r2.x; pu[u][5] = r2.y;                       \
    }                                                                            \
    _Pragma("unroll") for (int v = 0; v < 6; ++v) {                              \
        int pb = ((RV) * 6 + v) * 50 + (CB);                                     \
        float2 r0 = *(const float2*)&Pbuf[pb + 0];                               \
        float2 r1 = *(const float2*)&Pbuf[pb + 2];                               \
        float2 r2 = *(const float2*)&Pbuf[pb + 4];                               \
        pv[v][0] = r0.x; pv[v][1] = r0.y; pv[v][2] = r1.x;                       \
        pv[v][3] = r1.y; pv[v][4] = r2.x; pv[v][5] = r2.y;                       \
    }                                                                            \
    _Pragma("unroll") for (int u = 0; u < 6; ++u)                                \
        _Pragma("unroll") for (int v = 0; v < 6; ++v) {                          \
            float s = D[u][v];                                                   \
            s = fmaf(-pu[u][0], pv[v][0], s);                                    \
            s = fmaf(-pu[u][1], pv[v][1], s);                                    \
            s = fmaf(-pu[u][2], pv[v][2], s);                                    \
            s = fmaf(-pu[u][3], pv[v][3], s);                                    \
            s = fmaf(-pu[u][4], pv[v][4], s);                                    \
            s = fmaf(-pu[u][5], pv[v][5], s);                                    \
            D[u][v] = s;                                                         \
        }                                                                        \
} while (0)

#define STORE_TILE(D, TIEFF, TJEFF) do {                                         \
    _Pragma("unroll") for (int u = 0; u < 6; ++u) {                              \
        const int i2 = (TIEFF) * 6 + u;                                          \
        size_t rowp = gbase + (size_t)i2 * NMAT + (TJEFF) * 6;                   \
        _Pragma("unroll") for (int v = 0; v < 6; v += 2) {                       \
            int j0 = (TJEFF) * 6 + v;                                            \
            float a0 = D[u][v], a1 = D[u][v + 1];                                \
            if ((TIEFF) < (TJEFF)) { a0 = 0.0f; a1 = 0.0f; }                     \
            else if ((TIEFF) == (TJEFF)) {                                       \
                if (j0 > i2)     a0 = 0.0f;                                      \
                if (j0 + 1 > i2) a1 = 0.0f;                                      \
            }                                                                    \
            *(float2*)&outL[rowp + v] = make_float2(a0, a1);                     \
        }                                                                        \
    }                                                                            \
} while (0)

#define LOAD_TILE(D, TIEFF, TJEFF) do {                                          \
    _Pragma("unroll") for (int u = 0; u < 6; ++u) {                              \
        size_t rowp = gbase + (size_t)((TIEFF) * 6 + u) * NMAT + (TJEFF) * 6;    \
        float2 p0 = *(const float2*)&outG[rowp + 0];                             \
        float2 p1 = *(const float2*)&outG[rowp + 2];                             \
        float2 p2 = *(const float2*)&outG[rowp + 4];                             \
        D[u][0] = p0.x; D[u][1] = p0.y; D[u][2] = p1.x;                          \
        D[u][3] = p1.y; D[u][4] = p2.x; D[u][5] = p2.y;                          \
    }                                                                            \
} while (0)

__launch_bounds__(256)
__global__ void chol_kernel(const float* __restrict__ outG,
                            float* __restrict__ outL)
{
    const int w    = threadIdx.x >> 6;   // wave id 0..3 -> matrix
    const int lane = threadIdx.x & 63;
    const int wi   = lane >> 3;          // 0..7 row-tile
    const int wj   = lane & 7;           // 0..7 col-tile
    const int b    = blockIdx.x * 4 + w;
    const size_t gbase = (size_t)b * (NMAT * NMAT);

    __shared__ float spanel_all[4][48][12];  // transient panel (rows 0..47)
    __shared__ float sPbuf_all[4][48][50];   // persistent T10/T11 panels (even stride)
    __shared__ float sL6_all[4][6][8];
    __shared__ float srinv_all[4][8];
    float* panel = &spanel_all[w][0][0];
    float* Pbuf  = &sPbuf_all[w][0][0];
    float* L6p   = &sL6_all[w][0][0];
    float* rinvp = &srinv_all[w][0];

    float acc00[6][6], acc10[6][6];

    LOAD_TILE(acc00, wi,     wj);
    LOAD_TILE(acc10, 8 + wi, wj);

    // ---- first half: factor T00, solve T10 panels (persist-only to Pbuf) ----
    #pragma unroll 1
    for (int jb = 0; jb < 8; ++jb) {
        const int J = jb;
        if (wi == J && wj == J) PHASE_A(acc00);
        SBAR;
        if (wj == J && wi > J) PHASE_B(acc00, wi);
        if (wj == J)           { PHASE_B_SOLVE(acc10); PERSIST10(acc10, J * 6); }
        SBAR;
        if (wj > J && wi >= wj) PHASE_C(acc00, wi, wj);
        if (wj > J)             PHASE_C_MIX(acc10, wi, wj, J * 6);
        SBAR;
    }

    // ---- acc00/acc10 final: store, freeing registers ----
    STORE_TILE(acc00, wi,     wj);
    STORE_TILE(acc10, 8 + wi, wj);
    #pragma unroll
    for (int u = 0; u < 6; ++u) {
        size_t rowp = gbase + (size_t)(wi * 6 + u) * NMAT + (8 + wj) * 6;
        *(float2*)&outL[rowp + 0] = make_float2(0.0f, 0.0f);
        *(float2*)&outL[rowp + 2] = make_float2(0.0f, 0.0f);
        *(float2*)&outL[rowp + 4] = make_float2(0.0f, 0.0f);
    }
    SBAR;

    // ---- load g11; apply 8 deferred rank-6 updates (jb asc, m asc) ----
    // READ-ONLY region (Pbuf complete); vectorized row-outer form.
    float acc11[6][6];
    LOAD_TILE(acc11, 8 + wi, 8 + wj);
    #pragma unroll 2
    for (int jb2 = 0; jb2 < 8; ++jb2) {
        if (wi >= wj) PHASE_C_PV(acc11, wi, wj, jb2 * 6);
    }
    SBAR;

    // ---- second half: panel rows shifted -48 (address-only change) ----
    #pragma unroll 1
    for (int jb = 8; jb < 16; ++jb) {
        const int J = jb - 8;
        if (wi == J && wj == J) PHASE_A(acc11);
        SBAR;
        if (wj == J && wi > J) PHASE_B(acc11, wi);
        SBAR;
        if (wj > J && wi >= wj) PHASE_C(acc11, wi, wj);
        SBAR;
    }

    STORE_TILE(acc11, 8 + wi, 8 + wj);
}

extern "C" void kernel_launch(void* const* d_in, const int* in_sizes, int n_in,
                              void* d_out, int out_size, void* d_ws, size_t ws_size,
                              hipStream_t stream) {
    const float* kp     = (const float*)d_in[0];
    const float* aug    = (const float*)d_in[1];
    const float* scales = (const float*)d_in[2];
    const float* nug    = (const float*)d_in[3];
    float* out = (float*)d_out;
    unsigned* ws = (unsigned*)d_ws;

    float* outG = out;
    float* outL = out + (size_t)NB * NMAT * NMAT;

    hipMemsetAsync(ws, 0xFF, 4, stream);
    minnz_kernel<<<(NB + 255) / 256, 256, 0, stream>>>(scales, ws);
    gram_kernel<<<NB, 256, 0, stream>>>(kp, aug, scales, nug, ws, out);
    chol_kernel<<<NB / 4, 256, 0, stream>>>(outG, outL);
}